// Round 5
// baseline (878.469 us; speedup 1.0000x reference)
//
#include <hip/hip_runtime.h>
#include <math.h>

#define NN 4096
#define NITER 20

// u_0 = 1.0 (fp32 copy used by iteration kernels).
__global__ void k_init(float* uf) {
    int i = blockIdx.x * blockDim.x + threadIdx.x;
    if (i < NN) uf[i] = 1.0f;
}

// ET[j][i] = exp(W[i][j]) via 64x64 LDS tile transpose. grid = 4096 x 256.
__global__ __launch_bounds__(256) void k_expT(const float* __restrict__ W,
                                              float* __restrict__ ET) {
    __shared__ float tile[64][65];  // +1 pad breaks bank conflicts
    const int tx = threadIdx.x;
    const int c4 = (tx & 15) * 4;
    const int r0 = tx >> 4;
    const int tileR = (blockIdx.x & 63) * 64;   // W row block
    const int tileC = (blockIdx.x >> 6) * 64;   // W col block

    #pragma unroll
    for (int it = 0; it < 4; ++it) {
        int r = r0 + it * 16;
        float4 w = *(const float4*)(W + (size_t)(tileR + r) * NN + tileC + c4);
        tile[c4 + 0][r] = expf(w.x);
        tile[c4 + 1][r] = expf(w.y);
        tile[c4 + 2][r] = expf(w.z);
        tile[c4 + 3][r] = expf(w.w);
    }
    __syncthreads();
    #pragma unroll
    for (int it = 0; it < 4; ++it) {
        int rr = r0 + it * 16;
        float4 e;
        e.x = tile[rr][c4 + 0];
        e.y = tile[rr][c4 + 1];
        e.z = tile[rr][c4 + 2];
        e.w = tile[rr][c4 + 3];
        *(float4*)(ET + (size_t)(tileC + rr) * NN + tileR + c4) = e;
    }
}

// One FULL Sinkhorn iteration, ONE sweep over ET. Deterministic (no atomics).
// grid = 512 blocks x 512 thr (8 waves). Block b owns columns j in [8b, 8b+8).
// Phase 1: wave w = column j: s_j = sum_i ET[j][i]*u[i]  (contiguous reads,
//          fp64 accumulate, fixed butterfly). vlast[j] = s_j (fp64).
// Phase 2: wave w = rows [512w, 512w+512): r_i = sum_c ET[j_c][i]*(1/s_c),
//          8 fp64 registers/lane, one partial vector per block (plain stores).
__global__ __launch_bounds__(512) void k_iter2(const float* __restrict__ ET,
                                               const float* __restrict__ uf,
                                               double* __restrict__ partials,
                                               double* __restrict__ vlast) {
    __shared__ float u_lds[NN];   // 16 KiB
    __shared__ float sinv[8];
    const int tid = threadIdx.x;
    ((float4*)u_lds)[tid]       = ((const float4*)uf)[tid];
    ((float4*)u_lds)[tid + 512] = ((const float4*)uf)[tid + 512];
    __syncthreads();

    const int w = tid >> 6, l = tid & 63;
    const int j = blockIdx.x * 8 + w;
    const float4* ep = (const float4*)(ET + (size_t)j * NN) + l;
    const float4* up = (const float4*)u_lds + l;

    double a0 = 0.0, a1 = 0.0, a2 = 0.0, a3 = 0.0;
    #pragma unroll
    for (int k = 0; k < 16; ++k) {
        float4 e  = ep[k * 64];    // 1 KiB/wave, contiguous 16 KiB per column
        float4 uu = up[k * 64];    // ds_read_b128
        a0 = fma((double)e.x, (double)uu.x, a0);
        a1 = fma((double)e.y, (double)uu.y, a1);
        a2 = fma((double)e.z, (double)uu.z, a2);
        a3 = fma((double)e.w, (double)uu.w, a3);
    }
    double acc = (a0 + a1) + (a2 + a3);
    #pragma unroll
    for (int off = 32; off > 0; off >>= 1)
        acc += __shfl_xor(acc, off, 64);       // fixed butterfly order
    if (l == 0) { vlast[j] = acc; sinv[w] = (float)(1.0 / acc); }
    __syncthreads();

    // Phase 2: same 256 KiB, row-major chunks (L2-hot re-read).
    const int iA = w * 512 + l * 4;            // rows [512w, 512w+256)
    const int iB = iA + 256;                   // rows [512w+256, 512w+512)
    const float* base = ET + (size_t)blockIdx.x * 8 * NN;
    double rA0 = 0, rA1 = 0, rA2 = 0, rA3 = 0;
    double rB0 = 0, rB1 = 0, rB2 = 0, rB3 = 0;
    #pragma unroll
    for (int c = 0; c < 8; ++c) {
        float4 ea = *(const float4*)(base + (size_t)c * NN + iA);
        float4 eb = *(const float4*)(base + (size_t)c * NN + iB);
        double inv = (double)sinv[c];          // LDS broadcast, wave-uniform
        rA0 = fma((double)ea.x, inv, rA0);
        rA1 = fma((double)ea.y, inv, rA1);
        rA2 = fma((double)ea.z, inv, rA2);
        rA3 = fma((double)ea.w, inv, rA3);
        rB0 = fma((double)eb.x, inv, rB0);
        rB1 = fma((double)eb.y, inv, rB1);
        rB2 = fma((double)eb.z, inv, rB2);
        rB3 = fma((double)eb.w, inv, rB3);
    }
    double* pp = partials + (size_t)blockIdx.x * NN;
    *(double2*)(pp + iA)     = double2{rA0, rA1};
    *(double2*)(pp + iA + 2) = double2{rA2, rA3};
    *(double2*)(pp + iB)     = double2{rB0, rB1};
    *(double2*)(pp + iB + 2) = double2{rB2, rB3};
}

// Fixed-order partial reduction: u[i] = 1 / sum_b partials[b][i].
// grid = 64 blocks x 256 thr; 64 rows/block, 4 threads/row (quarters), LDS tree.
__global__ __launch_bounds__(256) void k_ured(const double* __restrict__ partials,
                                              double* __restrict__ u64,
                                              float* __restrict__ uf) {
    __shared__ double lds[4][64];
    const int r = threadIdx.x & 63;
    const int q = threadIdx.x >> 6;
    const int i = blockIdx.x * 64 + r;

    double s0 = 0.0, s1 = 0.0;
    const int b0 = q * 128;
    #pragma unroll 4
    for (int b = 0; b < 128; b += 2) {
        s0 += partials[(size_t)(b0 + b) * NN + i];       // 512B/wave, coalesced
        s1 += partials[(size_t)(b0 + b + 1) * NN + i];
    }
    lds[q][r] = s0 + s1;
    __syncthreads();
    if (q == 0) {
        double s = (lds[0][r] + lds[1][r]) + (lds[2][r] + lds[3][r]);  // fixed order
        double u = 1.0 / s;
        u64[i] = u;
        uf[i] = (float)u;
    }
}

// Final: P = exp(W + lv[j] + lu[i]); hard = one-hot(argmax_j (W + lv[j])).
__global__ __launch_bounds__(1024) void k_final(const float* __restrict__ W,
                                                const double* __restrict__ vlast,
                                                const double* __restrict__ u64,
                                                float* __restrict__ P,
                                                float* __restrict__ H) {
    __shared__ double lv[NN];  // 32 KiB
    for (int j = threadIdx.x; j < NN; j += 1024)
        lv[j] = -log(vlast[j]);
    __syncthreads();

    const int l  = threadIdx.x & 63;
    const int wv = threadIdx.x >> 6;
    const int i  = blockIdx.x * 16 + wv;
    const float4* wp = (const float4*)(W + (size_t)i * NN) + l;
    float4* pp = (float4*)(P + (size_t)i * NN) + l;
    float4* hp = (float4*)(H + (size_t)i * NN) + l;
    const double lu = log(u64[i]);   // = -R[i]

    double besty = -1e300;
    int bestj = 0;
    #pragma unroll 4
    for (int k = 0; k < 16; ++k) {
        float4 w = wp[k * 64];
        int jb = k * 256 + l * 4;
        double y0 = (double)w.x + lv[jb + 0];
        double y1 = (double)w.y + lv[jb + 1];
        double y2 = (double)w.z + lv[jb + 2];
        double y3 = (double)w.w + lv[jb + 3];
        float4 pv;
        pv.x = expf((float)(y0 + lu));
        pv.y = expf((float)(y1 + lu));
        pv.z = expf((float)(y2 + lu));
        pv.w = expf((float)(y3 + lu));
        pp[k * 64] = pv;
        if (y0 > besty) { besty = y0; bestj = jb + 0; }   // strict > = first index
        if (y1 > besty) { besty = y1; bestj = jb + 1; }
        if (y2 > besty) { besty = y2; bestj = jb + 2; }
        if (y3 > besty) { besty = y3; bestj = jb + 3; }
    }
    for (int off = 32; off > 0; off >>= 1) {
        double oy = __shfl_xor(besty, off, 64);
        int    oj = __shfl_xor(bestj, off, 64);
        if (oy > besty || (oy == besty && oj < bestj)) { besty = oy; bestj = oj; }
    }
    #pragma unroll 4
    for (int k = 0; k < 16; ++k) {
        int jb = k * 256 + l * 4;
        float4 hv;
        hv.x = (jb + 0 == bestj) ? 1.0f : 0.0f;
        hv.y = (jb + 1 == bestj) ? 1.0f : 0.0f;
        hv.z = (jb + 2 == bestj) ? 1.0f : 0.0f;
        hv.w = (jb + 3 == bestj) ? 1.0f : 0.0f;
        hp[k * 64] = hv;
    }
}

extern "C" void kernel_launch(void* const* d_in, const int* in_sizes, int n_in,
                              void* d_out, int out_size, void* d_ws, size_t ws_size,
                              hipStream_t stream) {
    const float* W = (const float*)d_in[0];
    float* out0 = (float*)d_out;                  // P_hat
    float* out1 = out0 + (size_t)NN * NN;         // P_hat_hard

    float*  ET       = (float*)d_ws;                         // NN*NN fp32 (64 MiB)
    double* partials = (double*)(ET + (size_t)NN * NN);      // 512*NN fp64 (16 MiB)
    double* u64      = partials + (size_t)512 * NN;          // NN fp64
    double* vlast    = u64 + NN;                             // NN fp64
    float*  uf       = (float*)(vlast + NN);                 // NN fp32

    k_init<<<(NN + 255) / 256, 256, 0, stream>>>(uf);
    k_expT<<<4096, 256, 0, stream>>>(W, ET);

    for (int t = 0; t < NITER; ++t) {
        k_iter2<<<512, 512, 0, stream>>>(ET, uf, partials, vlast);
        k_ured<<<64, 256, 0, stream>>>(partials, u64, uf);
    }
    k_final<<<256, 1024, 0, stream>>>(W, vlast, u64, out0, out1);
}